// Round 9
// baseline (100.469 us; speedup 1.0000x reference)
//
#include <hip/hip_runtime.h>

// Problem constants: B=4, N=256, E=512, fp32.
#define B_ 4
#define N_ 256
#define E_ 512

// ws float layout:
//   QwT  [256*256]          @ 0
//   Gpart[16][256*256]      @ 65536        (slab = kq*4+b)
//   Spart[16][256*256]      @ 1114112     (slab = kq*4+b; kq<=it written)
//   Tpart[16][256*256]      @ 2162688     (slab = kp*4+b; kp<=it written)
#define OFF_GP 65536
#define OFF_SP 1114112
#define OFF_TP 2162688

// ---------------------------------------------------------------------------
// prep_kernel: grid (4,4,17), block (16,16).  [unchanged, proven]
//  bz 0..15: split-K Gram partial; bz==16: Qw transpose.
// ---------------------------------------------------------------------------
__global__ __launch_bounds__(256) void prep_kernel(
    const float* __restrict__ X, const float* __restrict__ Qw,
    float* __restrict__ QwT, float* __restrict__ Gpart) {

    const int bx = blockIdx.x, by = blockIdx.y, bz = blockIdx.z;
    const int tx = threadIdx.x, ty = threadIdx.y;
    const int tid = ty * 16 + tx;

    if (bz == 16) {
        __shared__ float tt[64][68];
        const int r = tid >> 2, c0 = tid & 3;
#pragma unroll
        for (int cc = 0; cc < 4; ++cc) {
            const int c = (c0 + cc * 4) * 4;
            const float4 v = *(const float4*)&Qw[(by * 64 + r) * N_ + bx * 64 + c];
            tt[c + 0][r] = v.x; tt[c + 1][r] = v.y;
            tt[c + 2][r] = v.z; tt[c + 3][r] = v.w;
        }
        __syncthreads();
#pragma unroll
        for (int cc = 0; cc < 4; ++cc) {
            const int c = (c0 + cc * 4) * 4;
            const float4 v = *(const float4*)&tt[r][c];
            *(float4*)&QwT[(bx * 64 + r) * N_ + by * 64 + c] = v;
        }
        return;
    }

    const int b = bz >> 2, kq = bz & 3;
    const float* __restrict__ Xb = X + (size_t)b * N_ * E_;
    __shared__ float At[32][68];
    __shared__ float Bt[32][68];
    float acc[4][4] = {};
    const int r = tid >> 2, c0 = tid & 3;

    for (int k0 = kq * 128; k0 < kq * 128 + 128; k0 += 32) {
        {
            const float4 va = *(const float4*)&Xb[(size_t)(by * 64 + r) * E_ + k0 + c0 * 8];
            const float4 vb = *(const float4*)&Xb[(size_t)(by * 64 + r) * E_ + k0 + c0 * 8 + 4];
            At[c0*8+0][r] = va.x; At[c0*8+1][r] = va.y; At[c0*8+2][r] = va.z; At[c0*8+3][r] = va.w;
            At[c0*8+4][r] = vb.x; At[c0*8+5][r] = vb.y; At[c0*8+6][r] = vb.z; At[c0*8+7][r] = vb.w;
            const float4 wa = *(const float4*)&Xb[(size_t)(bx * 64 + r) * E_ + k0 + c0 * 8];
            const float4 wb = *(const float4*)&Xb[(size_t)(bx * 64 + r) * E_ + k0 + c0 * 8 + 4];
            Bt[c0*8+0][r] = wa.x; Bt[c0*8+1][r] = wa.y; Bt[c0*8+2][r] = wa.z; Bt[c0*8+3][r] = wa.w;
            Bt[c0*8+4][r] = wb.x; Bt[c0*8+5][r] = wb.y; Bt[c0*8+6][r] = wb.z; Bt[c0*8+7][r] = wb.w;
        }
        __syncthreads();
#pragma unroll
        for (int kk = 0; kk < 32; ++kk) {
            const float4 a  = *(const float4*)&At[kk][ty * 4];
            const float4 bb = *(const float4*)&Bt[kk][tx * 4];
            acc[0][0] += a.x*bb.x; acc[0][1] += a.x*bb.y; acc[0][2] += a.x*bb.z; acc[0][3] += a.x*bb.w;
            acc[1][0] += a.y*bb.x; acc[1][1] += a.y*bb.y; acc[1][2] += a.y*bb.z; acc[1][3] += a.y*bb.w;
            acc[2][0] += a.z*bb.x; acc[2][1] += a.z*bb.y; acc[2][2] += a.z*bb.z; acc[2][3] += a.z*bb.w;
            acc[3][0] += a.w*bb.x; acc[3][1] += a.w*bb.y; acc[3][2] += a.w*bb.z; acc[3][3] += a.w*bb.w;
        }
        __syncthreads();
    }
    float* gout = Gpart + ((size_t)(kq * 4 + b) * N_ + by * 64 + ty * 4) * N_ + bx * 64 + tx * 4;
#pragma unroll
    for (int qi = 0; qi < 4; ++qi)
        *(float4*)&gout[(size_t)qi * N_] =
            make_float4(acc[qi][0], acc[qi][1], acc[qi][2], acc[qi][3]);
}

// ---------------------------------------------------------------------------
// sgemm: Spart[kq][b][i][p] = sum_{n in kq-chunk, n<=i} G[i,n] * Kw[n,p]
// grid (pt=4, it=4, b*4+kq=16), block (16,16); active iff pt<=it && kq<=it.
// A-tile = sum of 4 Gpart slabs, diag-chunk masked.
// ---------------------------------------------------------------------------
__global__ __launch_bounds__(256) void sgemm_kernel(
    const float* __restrict__ Kw, float* __restrict__ ws) {

    const int pt = blockIdx.x, it = blockIdx.y;
    const int b  = blockIdx.z >> 2, kq = blockIdx.z & 3;
    if (pt > it || kq > it) return;

    const float* __restrict__ Gpart = ws + OFF_GP;
    float* __restrict__ Spart = ws + OFF_SP;

    const int tx = threadIdx.x, ty = threadIdx.y;
    const int tid = ty * 16 + tx;

    __shared__ float At[64][68];   // [k][i_loc]
    __shared__ float Bt[64][68];   // [k][p_loc]

    // ---- stage A: G rows it*64.., cols kq*64.., summed over 4 slabs, masked
    {
        const int i_loc = tid >> 2, c0 = tid & 3;   // k = c0*16 .. +15
        float av[16];
#pragma unroll
        for (int e = 0; e < 16; ++e) av[e] = 0.f;
#pragma unroll
        for (int q = 0; q < 4; ++q) {
            const float* src = Gpart + ((size_t)(q * 4 + b) * N_ + it * 64 + i_loc) * N_
                             + kq * 64 + c0 * 16;
#pragma unroll
            for (int v = 0; v < 4; ++v) {
                const float4 f = *(const float4*)&src[v * 4];
                av[v*4+0] += f.x; av[v*4+1] += f.y; av[v*4+2] += f.z; av[v*4+3] += f.w;
            }
        }
        if (kq == it) {
#pragma unroll
            for (int e = 0; e < 16; ++e)
                if (c0 * 16 + e > i_loc) av[e] = 0.f;
        }
#pragma unroll
        for (int e = 0; e < 16; ++e) At[c0 * 16 + e][i_loc] = av[e];
    }
    // ---- stage B: Kw rows kq*64.., cols pt*64..
    {
        const int k = tid >> 2, c0 = tid & 3;
        const float* src = Kw + (size_t)(kq * 64 + k) * N_ + pt * 64 + c0 * 16;
#pragma unroll
        for (int v = 0; v < 4; ++v)
            *(float4*)&Bt[k][c0 * 16 + v * 4] = *(const float4*)&src[v * 4];
    }
    __syncthreads();

    float acc[4][4] = {};
#pragma unroll 8
    for (int kk = 0; kk < 64; ++kk) {
        const float4 a  = *(const float4*)&At[kk][ty * 4];
        const float4 bb = *(const float4*)&Bt[kk][tx * 4];
        acc[0][0] += a.x*bb.x; acc[0][1] += a.x*bb.y; acc[0][2] += a.x*bb.z; acc[0][3] += a.x*bb.w;
        acc[1][0] += a.y*bb.x; acc[1][1] += a.y*bb.y; acc[1][2] += a.y*bb.z; acc[1][3] += a.y*bb.w;
        acc[2][0] += a.z*bb.x; acc[2][1] += a.z*bb.y; acc[2][2] += a.z*bb.z; acc[2][3] += a.z*bb.w;
        acc[3][0] += a.w*bb.x; acc[3][1] += a.w*bb.y; acc[3][2] += a.w*bb.z; acc[3][3] += a.w*bb.w;
    }

    float* sout = Spart + ((size_t)(kq * 4 + b) * N_ + it * 64 + ty * 4) * N_ + pt * 64 + tx * 4;
#pragma unroll
    for (int ri = 0; ri < 4; ++ri)
        *(float4*)&sout[(size_t)ri * N_] =
            make_float4(acc[ri][0], acc[ri][1], acc[ri][2], acc[ri][3]);
}

// ---------------------------------------------------------------------------
// tgemm: Tpart[kp][b][i][n] = sum_{p in kp-chunk, p<=i} S[i,p] * QwT[p,n]
// grid (nt=4, it=4, b*4+kp=16), block (16,16); active iff nt<=it && kp<=it.
// A-tile = sum of (it+1) Spart slabs, diag-chunk masked.
// ---------------------------------------------------------------------------
__global__ __launch_bounds__(256) void tgemm_kernel(
    const float* __restrict__ ws_c, float* __restrict__ ws) {

    const int nt = blockIdx.x, it = blockIdx.y;
    const int b  = blockIdx.z >> 2, kp = blockIdx.z & 3;
    if (nt > it || kp > it) return;

    const float* __restrict__ QwT   = ws_c;
    const float* __restrict__ Spart = ws_c + OFF_SP;
    float* __restrict__ Tpart = ws + OFF_TP;

    const int tx = threadIdx.x, ty = threadIdx.y;
    const int tid = ty * 16 + tx;

    __shared__ float At[64][68];
    __shared__ float Bt[64][68];

    // ---- stage A: S rows it*64.., cols kp*64.., summed over it+1 slabs, masked
    {
        const int i_loc = tid >> 2, c0 = tid & 3;
        float av[16];
#pragma unroll
        for (int e = 0; e < 16; ++e) av[e] = 0.f;
        for (int q = 0; q <= it; ++q) {
            const float* src = Spart + ((size_t)(q * 4 + b) * N_ + it * 64 + i_loc) * N_
                             + kp * 64 + c0 * 16;
#pragma unroll
            for (int v = 0; v < 4; ++v) {
                const float4 f = *(const float4*)&src[v * 4];
                av[v*4+0] += f.x; av[v*4+1] += f.y; av[v*4+2] += f.z; av[v*4+3] += f.w;
            }
        }
        if (kp == it) {
#pragma unroll
            for (int e = 0; e < 16; ++e)
                if (c0 * 16 + e > i_loc) av[e] = 0.f;
        }
#pragma unroll
        for (int e = 0; e < 16; ++e) At[c0 * 16 + e][i_loc] = av[e];
    }
    // ---- stage B: QwT rows kp*64.., cols nt*64..
    {
        const int k = tid >> 2, c0 = tid & 3;
        const float* src = QwT + (size_t)(kp * 64 + k) * N_ + nt * 64 + c0 * 16;
#pragma unroll
        for (int v = 0; v < 4; ++v)
            *(float4*)&Bt[k][c0 * 16 + v * 4] = *(const float4*)&src[v * 4];
    }
    __syncthreads();

    float acc[4][4] = {};
#pragma unroll 8
    for (int kk = 0; kk < 64; ++kk) {
        const float4 a  = *(const float4*)&At[kk][ty * 4];
        const float4 bb = *(const float4*)&Bt[kk][tx * 4];
        acc[0][0] += a.x*bb.x; acc[0][1] += a.x*bb.y; acc[0][2] += a.x*bb.z; acc[0][3] += a.x*bb.w;
        acc[1][0] += a.y*bb.x; acc[1][1] += a.y*bb.y; acc[1][2] += a.y*bb.z; acc[1][3] += a.y*bb.w;
        acc[2][0] += a.z*bb.x; acc[2][1] += a.z*bb.y; acc[2][2] += a.z*bb.z; acc[2][3] += a.z*bb.w;
        acc[3][0] += a.w*bb.x; acc[3][1] += a.w*bb.y; acc[3][2] += a.w*bb.z; acc[3][3] += a.w*bb.w;
    }

    float* tout = Tpart + ((size_t)(kp * 4 + b) * N_ + it * 64 + ty * 4) * N_ + nt * 64 + tx * 4;
#pragma unroll
    for (int ri = 0; ri < 4; ++ri)
        *(float4*)&tout[(size_t)ri * N_] =
            make_float4(acc[ri][0], acc[ri][1], acc[ri][2], acc[ri][3]);
}

// ---------------------------------------------------------------------------
// final: rows i in 32-row tile rt, cols m in 64-col tile mt.
//   fit[i][m] = sum_{n<=i} T[i,n] X[n,m];  avg[i] = sum_{n<=i} T[i,n] G[i,n]
//   out = X[i][m] * (1 + fit - avg).  T,G reconstructed from partial slabs.
// grid (mt=8, rt=8, b=4), block (16,16), frag 2x4.
// ---------------------------------------------------------------------------
__global__ __launch_bounds__(256) void final_kernel(
    const float* __restrict__ X, const float* __restrict__ ws_c,
    float* __restrict__ out) {

    const int mt = blockIdx.x, rt = blockIdx.y, b = blockIdx.z;
    const int it_eff = rt >> 1;            // 64-row i-tile index
    const int ibase  = (rt & 1) * 32;      // row offset inside the i-tile

    const float* __restrict__ Gpart = ws_c + OFF_GP;
    const float* __restrict__ Tpart = ws_c + OFF_TP;
    const float* __restrict__ Xb = X + (size_t)b * N_ * E_;

    const int tx = threadIdx.x, ty = threadIdx.y;
    const int tid = ty * 16 + tx;

    __shared__ float At[64][36];           // [k][row 0..31]
    __shared__ float Bt[64][68];           // [k][m_loc]
    __shared__ float avr[32][9];

    float acc[2][4] = {};
    float avgacc = 0.f;

    for (int kn = 0; kn <= it_eff; ++kn) {
        // ---- stage A: masked T rows rt*32.., cols kn*64.. + avg accumulation
        {
            const int r = tid >> 3, c0 = tid & 7;   // k = c0*8 .. +7
            float tvv[8], gvv[8];
#pragma unroll
            for (int e = 0; e < 8; ++e) { tvv[e] = 0.f; gvv[e] = 0.f; }
            for (int q = 0; q <= it_eff; ++q) {
                const float* src = Tpart + ((size_t)(q * 4 + b) * N_ + rt * 32 + r) * N_
                                 + kn * 64 + c0 * 8;
#pragma unroll
                for (int v = 0; v < 2; ++v) {
                    const float4 f = *(const float4*)&src[v * 4];
                    tvv[v*4+0] += f.x; tvv[v*4+1] += f.y; tvv[v*4+2] += f.z; tvv[v*4+3] += f.w;
                }
            }
#pragma unroll
            for (int q = 0; q < 4; ++q) {
                const float* src = Gpart + ((size_t)(q * 4 + b) * N_ + rt * 32 + r) * N_
                                 + kn * 64 + c0 * 8;
#pragma unroll
                for (int v = 0; v < 2; ++v) {
                    const float4 f = *(const float4*)&src[v * 4];
                    gvv[v*4+0] += f.x; gvv[v*4+1] += f.y; gvv[v*4+2] += f.z; gvv[v*4+3] += f.w;
                }
            }
            if (kn == it_eff) {
#pragma unroll
                for (int e = 0; e < 8; ++e)
                    if (c0 * 8 + e > ibase + r) tvv[e] = 0.f;
            }
#pragma unroll
            for (int e = 0; e < 8; ++e) {
                avgacc += tvv[e] * gvv[e];
                At[c0 * 8 + e][r] = tvv[e];
            }
        }
        // ---- stage B: X rows kn*64.., cols mt*64..
        {
            const int k = tid >> 2, c0 = tid & 3;
            const float* src = Xb + (size_t)(kn * 64 + k) * E_ + mt * 64 + c0 * 16;
#pragma unroll
            for (int v = 0; v < 4; ++v)
                *(float4*)&Bt[k][c0 * 16 + v * 4] = *(const float4*)&src[v * 4];
        }
        __syncthreads();

#pragma unroll 8
        for (int kk = 0; kk < 64; ++kk) {
            const float2 a  = *(const float2*)&At[kk][ty * 2];
            const float4 bb = *(const float4*)&Bt[kk][tx * 4];
            acc[0][0] += a.x*bb.x; acc[0][1] += a.x*bb.y; acc[0][2] += a.x*bb.z; acc[0][3] += a.x*bb.w;
            acc[1][0] += a.y*bb.x; acc[1][1] += a.y*bb.y; acc[1][2] += a.y*bb.z; acc[1][3] += a.y*bb.w;
        }
        __syncthreads();   // safe to overwrite LDS next iteration
    }

    avr[tid >> 3][tid & 7] = avgacc;
    __syncthreads();

#pragma unroll
    for (int ri = 0; ri < 2; ++ri) {
        const int row = ty * 2 + ri;               // 0..31
        float avg = 0.f;
#pragma unroll
        for (int c = 0; c < 8; ++c) avg += avr[row][c];
        const int gi = rt * 32 + row;
        const float4 xv = *(const float4*)&Xb[(size_t)gi * E_ + mt * 64 + tx * 4];
        float4 ov;
        ov.x = xv.x * (1.f + acc[ri][0] - avg);
        ov.y = xv.y * (1.f + acc[ri][1] - avg);
        ov.z = xv.z * (1.f + acc[ri][2] - avg);
        ov.w = xv.w * (1.f + acc[ri][3] - avg);
        *(float4*)&out[((size_t)b * N_ + gi) * E_ + mt * 64 + tx * 4] = ov;
    }
}

// ---------------------------------------------------------------------------
extern "C" void kernel_launch(void* const* d_in, const int* in_sizes, int n_in,
                              void* d_out, int out_size, void* d_ws, size_t ws_size,
                              hipStream_t stream) {
    const float* X  = (const float*)d_in[0];   // (B,N,E)
    const float* Qw = (const float*)d_in[1];   // (N,N)
    const float* Kw = (const float*)d_in[2];   // (N,N)
    float* out = (float*)d_out;                // (B,N,E)
    float* ws  = (float*)d_ws;

    float* QwT   = ws;
    float* Gpart = ws + OFF_GP;

    prep_kernel <<<dim3(4, 4, 17), dim3(16, 16), 0, stream>>>(X, Qw, QwT, Gpart);
    sgemm_kernel<<<dim3(4, 4, 16), dim3(16, 16), 0, stream>>>(Kw, ws);
    tgemm_kernel<<<dim3(4, 4, 16), dim3(16, 16), 0, stream>>>(ws, ws);
    final_kernel<<<dim3(8, 8, 4),  dim3(16, 16), 0, stream>>>(X, ws, out);
}